// Round 5
// baseline (13064.493 us; speedup 1.0000x reference)
//
#include <hip/hip_runtime.h>
#include <hip/hip_bf16.h>
#include <math.h>

// Problem constants
#define B_  32
#define C_  256
#define H_  64
#define W_  64
#define K_  17
#define HW_ 4096

// Output layout (flat concat of heat, off, var, fw, coords, scores)
#define HEAT_OFF  0
#define OFF_OFF   2228224
#define VAR_OFF   6684672
#define FW_OFF    8912896
#define COORD_OFF 8912897
#define SCORE_OFF 8913985

#define BN_SCALE 0.9999950000374997f

typedef __attribute__((ext_vector_type(8))) short  bf16x8;
typedef __attribute__((ext_vector_type(4))) float  f32x4;

__device__ __forceinline__ unsigned short f2bf(float x) {
  unsigned int u = __float_as_uint(x);
  u = u + 0x7fffu + ((u >> 16) & 1u);
  return (unsigned short)(u >> 16);
}
__device__ __forceinline__ float bf2f(unsigned short h) {
  return __uint_as_float(((unsigned int)h) << 16);
}

// ---------------------------------------------------------------------------
// Workspace layout (bytes).
// Activations: padded NHWC-interleaved [32][66][66][hi256|lo256] bf16 (1 KB/px)
// ---------------------------------------------------------------------------
#define XP_OFF  0ull                 // also F0 (fp32 NCHW) overlay later
#define S1_OFF  142737408ull
#define S2_OFF  285474816ull
#define WB_OFF  428212224ull
#define WS1_OFF (WB_OFF)             // [9][256][hi256|lo256] = 2359296 B
#define WS2_OFF (WB_OFF +  2359296ull)
#define WH1_OFF (WB_OFF +  4718592ull)
#define WO1_OFF (WB_OFF +  7077888ull)
#define WV1_OFF (WB_OFF +  9437184ull)   // [9][128][512] = 1179648
#define CG_OFF  (WB_OFF + 10616832ull)

// ---------------------------------------------------------------------------
// pack_x: fp32 NCHW -> padded NHWC interleaved hi/lo bf16
// ---------------------------------------------------------------------------
__global__ __launch_bounds__(256) void pack_x(
    const float* __restrict__ x, unsigned short* __restrict__ out) {
  __shared__ float s[128 * 66];
  const int b  = blockIdx.x / 66;
  const int pr = blockIdx.x % 66;
  const size_t obase = ((size_t)(b * 66 + pr) * 66) * 512;
  if (pr == 0 || pr == 65) {
    for (int i = threadIdx.x; i < 66 * 512; i += 256) out[obase + i] = 0;
    return;
  }
  const int y = pr - 1;
  for (int h = 0; h < 2; ++h) {
    __syncthreads();
    for (int i = threadIdx.x; i < 128 * 66; i += 256) {
      int c = i / 66, pc = i % 66;
      int xx = pc - 1;
      float v = (xx >= 0 && xx < 64)
          ? x[((size_t)b * 256 + h * 128 + c) * 4096 + y * 64 + xx] : 0.f;
      s[i] = v;
    }
    __syncthreads();
    for (int i = threadIdx.x; i < 66 * 128; i += 256) {
      int pc = i / 128, c = i % 128;
      float v = s[c * 66 + pc];
      unsigned short hb = f2bf(v);
      size_t o = obase + (size_t)pc * 512 + h * 128 + c;
      out[o]       = hb;
      out[o + 256] = f2bf(v - bf2f(hb));
    }
  }
}

// ---------------------------------------------------------------------------
// pack_w: OIHW fp32 -> [tap][co][hi ci 256 | lo ci 256] bf16
// ---------------------------------------------------------------------------
__global__ void pack_w(const float* __restrict__ w, unsigned short* __restrict__ out,
                       int COUT) {
  int i = blockIdx.x * 256 + threadIdx.x;
  int tot = COUT * 256 * 9;
  if (i >= tot) return;
  int co = i / (256 * 9);
  int r  = i - co * 256 * 9;
  int ci = r / 9;
  int k  = r - ci * 9;
  float v = w[i];
  unsigned short hb = f2bf(v);
  size_t o = ((size_t)k * COUT + co) * 512 + ci;
  out[o]       = hb;
  out[o + 256] = f2bf(v - bf2f(hb));
}

// ---------------------------------------------------------------------------
// zero_border: zero halo of a packed interleaved activation tensor
// ---------------------------------------------------------------------------
__global__ void zero_border(unsigned short* __restrict__ t) {
  int i = blockIdx.x * 256 + threadIdx.x;   // 32*260*512
  if (i >= 32 * 260 * 512) return;
  int c = i & 511;
  int p = i >> 9;
  int b = p / 260;
  int q = p - b * 260;
  int pr, pc;
  if (q < 66) { pr = 0; pc = q; }
  else if (q < 132) { pr = 65; pc = q - 66; }
  else { int u = q - 132; pr = 1 + (u >> 1); pc = (u & 1) * 65; }
  t[((size_t)(b * 66 + pr) * 66 + pc) * 512 + c] = 0;
}

// ---------------------------------------------------------------------------
// Split-bf16 3-pass MFMA 3x3 conv + BN + ReLU.
// Tile: 256 px (4 rows x 64) x 128 cout; 4 waves (2 m-halves x 2 n-halves).
// A: synchronous VGPR prefetch -> XOR-swizzled LDS, 128 B/px, no pad.
//    (global_load_lds with divergent LDS ptr was a 5x regression in R4.)
// B: register double-clocked, 144 B/co (hi64|lo64|pad16).
// OUTMODE 0: packed interleaved hi/lo bf16 (interior). OUTMODE 1: fp32 NCHW.
// ---------------------------------------------------------------------------
#define ABYTES 50688            // 396 px * 128 B
#define BBOFF  50688
#define SMEMB  69120            // + 128 co * 144 B

template <int COUT, int OUTMODE>
__global__ __launch_bounds__(256, 2) void conv3x3_mfma(
    const unsigned short* __restrict__ P, const unsigned short* __restrict__ Wt,
    const float* __restrict__ gam, const float* __restrict__ bet,
    unsigned short* __restrict__ Opk, float* __restrict__ Ofp) {
  constexpr int NB = COUT / 128;
  const int bid = blockIdx.x;
  int nblk, mb;
  if (NB == 2) { nblk = (bid >> 3) & 1; mb = (bid & 7) | ((bid >> 4) << 3); }
  else         { nblk = 0;              mb = bid; }
  const int b  = mb >> 4;
  const int yq = mb & 15;
  const int Y0 = yq * 4;

  const int tid  = threadIdx.x;
  const int lane = tid & 63;
  const int wv   = tid >> 6;
  const int l15  = lane & 15;
  const int quad = lane >> 4;
  const int mhalf = (wv & 1) * 128;
  const int nbase = (wv >> 1) * 64;

  __shared__ __align__(16) char smem[SMEMB];

  int pbase[8];
#pragma unroll
  for (int mi = 0; mi < 8; ++mi) {
    int px = mhalf + mi * 16 + l15;
    pbase[mi] = (px >> 6) * 66 + (px & 63);
  }
  int boff[4];
#pragma unroll
  for (int ni = 0; ni < 4; ++ni)
    boff[ni] = (nbase + ni * 16 + l15) * 144 + quad * 16;

  f32x4 acc[8][4];
#pragma unroll
  for (int mi = 0; mi < 8; ++mi)
#pragma unroll
    for (int ni = 0; ni < 4; ++ni) acc[mi][ni] = (f32x4)0.f;

  const size_t ibase = (size_t)(b * 66 + Y0) * 66;

  uint4 ipref[13], bpref[4];

  // A staging: 396 px * 8 groups of 16 B. Global read unswizzled (coalesced),
  // LDS write swizzled: slot gs = g ^ (p & 7)  ->  2-way max on reads (free).
  auto loadI = [&](int cc) {
#pragma unroll
    for (int j = 0; j < 13; ++j) {
      int idx = tid + j * 256;
      if (idx < 3168) {
        int p = idx >> 3, g = idx & 7;
        size_t goff = (ibase + p) * 512 + (g < 4 ? cc * 32 + g * 8
                                                 : 256 + cc * 32 + (g - 4) * 8);
        ipref[j] = *(const uint4*)(P + goff);
      }
    }
  };
  auto writeI = [&]() {
#pragma unroll
    for (int j = 0; j < 13; ++j) {
      int idx = tid + j * 256;
      if (idx < 3168) {
        int p = idx >> 3, g = idx & 7;
        int gs = g ^ (p & 7);
        *(uint4*)(smem + p * 128 + gs * 16) = ipref[j];
      }
    }
  };
  auto loadB = [&](int tt, int cc) {
#pragma unroll
    for (int j = 0; j < 4; ++j) {
      int idx = tid + j * 256;
      int co = idx >> 3, g = idx & 7;
      size_t goff = ((size_t)tt * COUT + nblk * 128 + co) * 512 +
                    (g < 4 ? cc * 32 + g * 8 : 256 + cc * 32 + (g - 4) * 8);
      bpref[j] = *(const uint4*)(Wt + goff);
    }
  };
  auto writeB = [&]() {
#pragma unroll
    for (int j = 0; j < 4; ++j) {
      int idx = tid + j * 256;
      int co = idx >> 3, g = idx & 7;
      *(uint4*)(smem + BBOFF + co * 144 + g * 16) = bpref[j];
    }
  };

  // ---- prologue ----
  loadI(0);
  loadB(0, 0);
  writeI();
  writeB();
  loadB(1, 0);
  __syncthreads();

  for (int c8 = 0; c8 < 8; ++c8) {
#pragma unroll
    for (int t = 0; t < 9; ++t) {
      if (t == 7 && c8 < 7) loadI(c8 + 1);

      const int offt = (t / 3) * 66 + (t % 3);
      bf16x8 bh[4], bl[4];
#pragma unroll
      for (int ni = 0; ni < 4; ++ni) {
        const char* bp = smem + BBOFF + boff[ni];
        bh[ni] = *(const bf16x8*)bp;
        bl[ni] = *(const bf16x8*)(bp + 64);
      }
#pragma unroll
      for (int mi = 0; mi < 8; ++mi) {
        int p  = pbase[mi] + offt;
        int sw = (quad ^ (p & 7)) << 4;
        bf16x8 ah = *(const bf16x8*)(smem + p * 128 + sw);
        bf16x8 al = *(const bf16x8*)(smem + p * 128 + (sw ^ 64));
#pragma unroll
        for (int ni = 0; ni < 4; ++ni) {
          acc[mi][ni] = __builtin_amdgcn_mfma_f32_16x16x32_bf16(ah, bh[ni], acc[mi][ni], 0, 0, 0);
          acc[mi][ni] = __builtin_amdgcn_mfma_f32_16x16x32_bf16(al, bh[ni], acc[mi][ni], 0, 0, 0);
          acc[mi][ni] = __builtin_amdgcn_mfma_f32_16x16x32_bf16(ah, bl[ni], acc[mi][ni], 0, 0, 0);
        }
      }

      if (!(c8 == 7 && t == 8)) {
        __syncthreads();                       // all waves done reading A/B
        writeB();                              // B for next slot
        if (t == 8) writeI();                  // A for next chunk
        int nt = t + 2, nc = c8;
        if (nt >= 9) { nt -= 9; ++nc; }
        if (nc > 7) { nc = 7; nt = 8; }
        loadB(nt, nc);
        __syncthreads();
      }
    }
  }

  // ---- epilogue: BN + ReLU ----
  __syncthreads();
  float sc[4], bi[4];
#pragma unroll
  for (int ni = 0; ni < 4; ++ni) {
    int co = nblk * 128 + nbase + ni * 16 + l15;
    sc[ni] = gam[co] * BN_SCALE;
    bi[ni] = bet[co];
  }

  if (OUTMODE == 0) {
    // 4 chunks = 4 output rows; LDS row: 64 px * (hi256|lo256 + 16 pad) = 528 B
    for (int c = 0; c < 4; ++c) {
      if ((wv & 1) == (c >> 1)) {
        int mib = (c & 1) * 4;
#pragma unroll
        for (int mm = 0; mm < 4; ++mm) {
          int mi = mib + mm;
#pragma unroll
          for (int ni = 0; ni < 4; ++ni) {
            int cofs = (nbase + ni * 16 + l15) * 2;
#pragma unroll
            for (int r = 0; r < 4; ++r) {
              int col = mm * 16 + quad * 4 + r;
              float v = fmaxf(acc[mi][ni][r] * sc[ni] + bi[ni], 0.f);
              unsigned short hb = f2bf(v);
              *(unsigned short*)(smem + col * 528 + cofs)       = hb;
              *(unsigned short*)(smem + col * 528 + 256 + cofs) = f2bf(v - bf2f(hb));
            }
          }
        }
      }
      __syncthreads();
#pragma unroll
      for (int j = 0; j < 8; ++j) {
        int idx = tid + j * 256;
        int px = idx >> 5, s = idx & 31;
        uint4 d = *(const uint4*)(smem + px * 528 + s * 16);
        size_t pg = (size_t)(b * 66 + Y0 + c + 1) * 66 + (px + 1);
        char* dst = (char*)Opk + pg * 1024 + nblk * 256 + s * 16 + ((s & 16) ? 256 : 0);
        *(uint4*)dst = d;
      }
      __syncthreads();
    }
  } else {
    // fp32 NCHW: 4 chunks of one row x 128 co; LDS: co*272 + col*4
    for (int c = 0; c < 4; ++c) {
      if ((wv & 1) == (c >> 1)) {
        int mib = (c & 1) * 4;
#pragma unroll
        for (int mm = 0; mm < 4; ++mm) {
          int mi = mib + mm;
          int pl = mm * 16 + quad * 4;
#pragma unroll
          for (int ni = 0; ni < 4; ++ni) {
            int co = nbase + ni * 16 + l15;
            f32x4 vv;
#pragma unroll
            for (int r = 0; r < 4; ++r)
              vv[r] = fmaxf(acc[mi][ni][r] * sc[ni] + bi[ni], 0.f);
            *(f32x4*)(smem + co * 272 + pl * 4) = vv;
          }
        }
      }
      __syncthreads();
#pragma unroll
      for (int j = 0; j < 8; ++j) {
        int idx = tid + j * 256;
        int co = idx >> 4, g = idx & 15;
        f32x4 d = *(const f32x4*)(smem + co * 272 + g * 16);
        size_t o = ((size_t)b * COUT + nblk * 128 + co) * 4096 + (Y0 + c) * 64 + g * 4;
        *(f32x4*)(Ofp + o) = d;
      }
      __syncthreads();
    }
  }
}

// ---------------------------------------------------------------------------
// 1x1 conv + bias (+ optional softplus), fp32 NCHW input
// ---------------------------------------------------------------------------
template <int CO, int CIN>
__global__ __launch_bounds__(256) void conv1x1_kernel(
    const float* __restrict__ in, const float* __restrict__ w,
    const float* __restrict__ bias, float* __restrict__ out, int do_softplus) {
  __shared__ float s_w[CO * CIN];
  const int b   = blockIdx.x >> 4;
  const int pix = ((blockIdx.x & 15) << 8) + threadIdx.x;
  for (int i = threadIdx.x; i < CO * CIN; i += 256) s_w[i] = w[i];
  __syncthreads();

  float acc[CO];
#pragma unroll
  for (int co = 0; co < CO; ++co) acc[co] = 0.f;

  const float* ip = in + (size_t)b * CIN * HW_ + pix;
  for (int ci = 0; ci < CIN; ++ci) {
    float v = ip[(size_t)ci * HW_];
#pragma unroll
    for (int co = 0; co < CO; ++co) acc[co] = fmaf(v, s_w[co * CIN + ci], acc[co]);
  }
  float* op = out + (size_t)b * CO * HW_ + pix;
#pragma unroll
  for (int co = 0; co < CO; ++co) {
    float x = acc[co] + bias[co];
    if (do_softplus) x = fmaxf(x, 0.f) + log1pf(expf(-fabsf(x)));
    op[(size_t)co * HW_] = x;
  }
}

// ---------------------------------------------------------------------------
// soft-argmax over each (b,k) 64x64 heatmap
// ---------------------------------------------------------------------------
__global__ __launch_bounds__(256) void soft_argmax_kernel(
    const float* __restrict__ heat, float* __restrict__ cg,
    float* __restrict__ scores) {
  const int bk = blockIdx.x;
  const float* h = heat + (size_t)bk * HW_;
  const int tid = threadIdx.x;
  __shared__ float sred[256];

  float v[16];
  float lmax = -INFINITY;
#pragma unroll
  for (int i = 0; i < 16; ++i) {
    v[i] = h[tid + (i << 8)];
    lmax = fmaxf(lmax, v[i]);
  }
  sred[tid] = lmax; __syncthreads();
  for (int s = 128; s > 0; s >>= 1) {
    if (tid < s) sred[tid] = fmaxf(sred[tid], sred[tid + s]);
    __syncthreads();
  }
  const float m = sred[0];
  __syncthreads();

  float s = 0.f, sx = 0.f, sy = 0.f;
#pragma unroll
  for (int i = 0; i < 16; ++i) {
    int idx = tid + (i << 8);
    float e = expf(v[i] - m);
    s += e;
    sx += e * (float)(idx & 63);
    sy += e * (float)(idx >> 6);
  }
  sred[tid] = s; __syncthreads();
  for (int st = 128; st > 0; st >>= 1) { if (tid < st) sred[tid] += sred[tid + st]; __syncthreads(); }
  const float S = sred[0]; __syncthreads();
  sred[tid] = sx; __syncthreads();
  for (int st = 128; st > 0; st >>= 1) { if (tid < st) sred[tid] += sred[tid + st]; __syncthreads(); }
  const float SX = sred[0]; __syncthreads();
  sred[tid] = sy; __syncthreads();
  for (int st = 128; st > 0; st >>= 1) { if (tid < st) sred[tid] += sred[tid + st]; __syncthreads(); }
  const float SY = sred[0];

  if (tid == 0) {
    cg[bk * 2]     = SX / S;
    cg[bk * 2 + 1] = SY / S;
    scores[bk]     = m;
  }
}

// ---------------------------------------------------------------------------
// local refine + blend + bilinear offset sampling + final coords; writes fw.
// ---------------------------------------------------------------------------
__global__ void refine_kernel(
    const float* __restrict__ heat, const float* __restrict__ off,
    const float* __restrict__ cg, const float* __restrict__ alpha_p,
    const float* __restrict__ fusion_p, float* __restrict__ coords_out,
    float* __restrict__ fw_out) {
  const int kp = blockIdx.x * 64 + threadIdx.x;
  const float fw = 1.f / (1.f + expf(-fusion_p[0]));
  if (kp == 0) fw_out[0] = fw;
  if (kp >= B_ * K_) return;

  const float a = 1.f / (1.f + expf(-alpha_p[0]));
  const float* h = heat + (size_t)kp * HW_;
  const float cgx = cg[kp * 2];
  const float cgy = cg[kp * 2 + 1];
  const int px = (int)rintf(fminf(fmaxf(cgx, 0.f), 63.f));
  const int py = (int)rintf(fminf(fmaxf(cgy, 0.f), 63.f));

  float vals[25];
  float m = -INFINITY;
#pragma unroll
  for (int dy = 0; dy < 5; ++dy) {
    int ya = py + dy - 2;
    int yc = min(max(ya, 0), 63);
#pragma unroll
    for (int dx = 0; dx < 5; ++dx) {
      int xa = px + dx - 2;
      int xc = min(max(xa, 0), 63);
      bool inb = (ya >= 0) && (ya < H_) && (xa >= 0) && (xa < W_);
      float val = inb ? h[yc * W_ + xc] : -INFINITY;
      vals[dy * 5 + dx] = val;
      m = fmaxf(m, val);
    }
  }
  float s = 0.f, rx = 0.f, ry = 0.f;
#pragma unroll
  for (int dy = 0; dy < 5; ++dy) {
    int ya = py + dy - 2;
    int yc = min(max(ya, 0), 63);
#pragma unroll
    for (int dx = 0; dx < 5; ++dx) {
      int xa = px + dx - 2;
      int xc = min(max(xa, 0), 63);
      float e = expf(vals[dy * 5 + dx] - m);
      s += e;
      rx += e * (float)xc;
      ry += e * (float)yc;
    }
  }
  rx /= s; ry /= s;

  float cx = a * cgx + (1.f - a) * rx;
  float cy = a * cgy + (1.f - a) * ry;

  const float ix = fminf(fmaxf(cx, 0.f), 63.f);
  const float iy = fminf(fmaxf(cy, 0.f), 63.f);
  const float x0 = floorf(ix), y0 = floorf(iy);
  const float wx = ix - x0, wy = iy - y0;
  const int x0i = min(max((int)x0, 0), 63);
  const int x1i = min(x0i + 1, 63);
  const int y0i = min(max((int)y0, 0), 63);
  const int y1i = min(y0i + 1, 63);

  float smp[2];
#pragma unroll
  for (int ch = 0; ch < 2; ++ch) {
    const float* oc = off + ((size_t)kp * 2 + ch) * HW_;
    float v00 = oc[y0i * W_ + x0i];
    float v01 = oc[y0i * W_ + x1i];
    float v10 = oc[y1i * W_ + x0i];
    float v11 = oc[y1i * W_ + x1i];
    smp[ch] = (1.f - wy) * ((1.f - wx) * v00 + wx * v01)
            + wy * ((1.f - wx) * v10 + wx * v11);
  }
  cx += fw * smp[0];
  cy += fw * smp[1];
  coords_out[kp * 2]     = cx;
  coords_out[kp * 2 + 1] = cy;
}

// ---------------------------------------------------------------------------
extern "C" void kernel_launch(void* const* d_in, const int* in_sizes, int n_in,
                              void* d_out, int out_size, void* d_ws, size_t ws_size,
                              hipStream_t stream) {
  const float* x    = (const float*)d_in[0];
  const float* w_s1 = (const float*)d_in[1];
  const float* g_s1 = (const float*)d_in[2];
  const float* b_s1 = (const float*)d_in[3];
  const float* w_s2 = (const float*)d_in[4];
  const float* g_s2 = (const float*)d_in[5];
  const float* b_s2 = (const float*)d_in[6];
  const float* w_h1 = (const float*)d_in[7];
  const float* g_h1 = (const float*)d_in[8];
  const float* b_h1 = (const float*)d_in[9];
  const float* w_h2 = (const float*)d_in[10];
  const float* c_h2 = (const float*)d_in[11];
  const float* w_o1 = (const float*)d_in[12];
  const float* g_o1 = (const float*)d_in[13];
  const float* b_o1 = (const float*)d_in[14];
  const float* w_o2 = (const float*)d_in[15];
  const float* c_o2 = (const float*)d_in[16];
  const float* w_v1 = (const float*)d_in[17];
  const float* g_v1 = (const float*)d_in[18];
  const float* b_v1 = (const float*)d_in[19];
  const float* w_v2 = (const float*)d_in[20];
  const float* c_v2 = (const float*)d_in[21];
  const float* alpha  = (const float*)d_in[22];
  const float* fusion = (const float*)d_in[23];

  float* out = (float*)d_out;
  char*  ws  = (char*)d_ws;

  unsigned short* XP  = (unsigned short*)(ws + XP_OFF);
  unsigned short* S1  = (unsigned short*)(ws + S1_OFF);
  unsigned short* S2  = (unsigned short*)(ws + S2_OFF);
  unsigned short* WS1 = (unsigned short*)(ws + WS1_OFF);
  unsigned short* WS2 = (unsigned short*)(ws + WS2_OFF);
  unsigned short* WH1 = (unsigned short*)(ws + WH1_OFF);
  unsigned short* WO1 = (unsigned short*)(ws + WO1_OFF);
  unsigned short* WV1 = (unsigned short*)(ws + WV1_OFF);
  float* F0  = (float*)(ws + 0);        // overlays XP (dead after s1 conv)
  float* cgb = (float*)(ws + CG_OFF);

  dim3 blk(256);

  // ---- pack inputs & weights, zero halos ----
  pack_x<<<32 * 66, blk, 0, stream>>>(x, XP);
  pack_w<<<2304, blk, 0, stream>>>(w_s1, WS1, 256);
  pack_w<<<2304, blk, 0, stream>>>(w_s2, WS2, 256);
  pack_w<<<2304, blk, 0, stream>>>(w_h1, WH1, 256);
  pack_w<<<2304, blk, 0, stream>>>(w_o1, WO1, 256);
  pack_w<<<1152, blk, 0, stream>>>(w_v1, WV1, 128);
  zero_border<<<16640, blk, 0, stream>>>(S1);
  zero_border<<<16640, blk, 0, stream>>>(S2);

  // ---- backbone convs (split-bf16 3-pass MFMA) ----
  conv3x3_mfma<256, 0><<<1024, blk, 0, stream>>>(XP, WS1, g_s1, b_s1, S1, nullptr);
  conv3x3_mfma<256, 0><<<1024, blk, 0, stream>>>(S1, WS2, g_s2, b_s2, S2, nullptr);
  conv3x3_mfma<256, 1><<<1024, blk, 0, stream>>>(S2, WH1, g_h1, b_h1, nullptr, F0);
  conv1x1_kernel<17, 256><<<512, blk, 0, stream>>>(F0, w_h2, c_h2, out + HEAT_OFF, 0);
  conv3x3_mfma<256, 1><<<1024, blk, 0, stream>>>(S2, WO1, g_o1, b_o1, nullptr, F0);
  conv1x1_kernel<34, 256><<<512, blk, 0, stream>>>(F0, w_o2, c_o2, out + OFF_OFF, 0);
  conv3x3_mfma<128, 1><<<512, blk, 0, stream>>>(S2, WV1, g_v1, b_v1, nullptr, F0);
  conv1x1_kernel<17, 128><<<512, blk, 0, stream>>>(F0, w_v2, c_v2, out + VAR_OFF, 1);

  // ---- heads ----
  soft_argmax_kernel<<<544, blk, 0, stream>>>(out + HEAT_OFF, cgb, out + SCORE_OFF);
  refine_kernel<<<9, dim3(64), 0, stream>>>(out + HEAT_OFF, out + OFF_OFF, cgb,
                                            alpha, fusion,
                                            out + COORD_OFF, out + FW_OFF);
}

// Round 6
// 7100.647 us; speedup vs baseline: 1.8399x; 1.8399x over previous
//
#include <hip/hip_runtime.h>
#include <hip/hip_bf16.h>
#include <math.h>

// Problem constants
#define B_  32
#define C_  256
#define H_  64
#define W_  64
#define K_  17
#define HW_ 4096

// Output layout (flat concat of heat, off, var, fw, coords, scores)
#define HEAT_OFF  0
#define OFF_OFF   2228224
#define VAR_OFF   6684672
#define FW_OFF    8912896
#define COORD_OFF 8912897
#define SCORE_OFF 8913985

#define BN_SCALE 0.9999950000374997f

typedef __attribute__((ext_vector_type(8))) short  bf16x8;
typedef __attribute__((ext_vector_type(4))) float  f32x4;

__device__ __forceinline__ unsigned short f2bf(float x) {
  unsigned int u = __float_as_uint(x);
  u = u + 0x7fffu + ((u >> 16) & 1u);
  return (unsigned short)(u >> 16);
}
__device__ __forceinline__ float bf2f(unsigned short h) {
  return __uint_as_float(((unsigned int)h) << 16);
}

// ---------------------------------------------------------------------------
// Workspace layout (bytes).
// Activations: padded NHWC-interleaved [32][66][66][hi256|lo256] bf16 (1 KB/px)
// ---------------------------------------------------------------------------
#define XP_OFF  0ull                 // also F0 (fp32 NCHW) overlay later
#define S1_OFF  142737408ull
#define S2_OFF  285474816ull
#define WB_OFF  428212224ull
#define WS1_OFF (WB_OFF)             // [9][256][hi256|lo256] = 2359296 B
#define WS2_OFF (WB_OFF +  2359296ull)
#define WH1_OFF (WB_OFF +  4718592ull)
#define WO1_OFF (WB_OFF +  7077888ull)
#define WV1_OFF (WB_OFF +  9437184ull)   // [9][128][512] = 1179648
#define CG_OFF  (WB_OFF + 10616832ull)

// ---------------------------------------------------------------------------
// pack_x: fp32 NCHW -> padded NHWC interleaved hi/lo bf16
// ---------------------------------------------------------------------------
__global__ __launch_bounds__(256) void pack_x(
    const float* __restrict__ x, unsigned short* __restrict__ out) {
  __shared__ float s[128 * 66];
  const int b  = blockIdx.x / 66;
  const int pr = blockIdx.x % 66;
  const size_t obase = ((size_t)(b * 66 + pr) * 66) * 512;
  if (pr == 0 || pr == 65) {
    for (int i = threadIdx.x; i < 66 * 512; i += 256) out[obase + i] = 0;
    return;
  }
  const int y = pr - 1;
  for (int h = 0; h < 2; ++h) {
    __syncthreads();
    for (int i = threadIdx.x; i < 128 * 66; i += 256) {
      int c = i / 66, pc = i % 66;
      int xx = pc - 1;
      float v = (xx >= 0 && xx < 64)
          ? x[((size_t)b * 256 + h * 128 + c) * 4096 + y * 64 + xx] : 0.f;
      s[i] = v;
    }
    __syncthreads();
    for (int i = threadIdx.x; i < 66 * 128; i += 256) {
      int pc = i / 128, c = i % 128;
      float v = s[c * 66 + pc];
      unsigned short hb = f2bf(v);
      size_t o = obase + (size_t)pc * 512 + h * 128 + c;
      out[o]       = hb;
      out[o + 256] = f2bf(v - bf2f(hb));
    }
  }
}

// ---------------------------------------------------------------------------
// pack_w: OIHW fp32 -> [tap][co][hi ci 256 | lo ci 256] bf16
// ---------------------------------------------------------------------------
__global__ void pack_w(const float* __restrict__ w, unsigned short* __restrict__ out,
                       int COUT) {
  int i = blockIdx.x * 256 + threadIdx.x;
  int tot = COUT * 256 * 9;
  if (i >= tot) return;
  int co = i / (256 * 9);
  int r  = i - co * 256 * 9;
  int ci = r / 9;
  int k  = r - ci * 9;
  float v = w[i];
  unsigned short hb = f2bf(v);
  size_t o = ((size_t)k * COUT + co) * 512 + ci;
  out[o]       = hb;
  out[o + 256] = f2bf(v - bf2f(hb));
}

// ---------------------------------------------------------------------------
// zero_border: zero halo of a packed interleaved activation tensor
// ---------------------------------------------------------------------------
__global__ void zero_border(unsigned short* __restrict__ t) {
  int i = blockIdx.x * 256 + threadIdx.x;   // 32*260*512
  if (i >= 32 * 260 * 512) return;
  int c = i & 511;
  int p = i >> 9;
  int b = p / 260;
  int q = p - b * 260;
  int pr, pc;
  if (q < 66) { pr = 0; pc = q; }
  else if (q < 132) { pr = 65; pc = q - 66; }
  else { int u = q - 132; pr = 1 + (u >> 1); pc = (u & 1) * 65; }
  t[((size_t)(b * 66 + pr) * 66 + pc) * 512 + c] = 0;
}

// ---------------------------------------------------------------------------
// Split-bf16 3-pass MFMA 3x3 conv + BN + ReLU.
// R2-proven tile: 128 px (2 rows x 64) x 128 cout; 4 waves (2 m x 2 n).
// acc[4][4] (64 AGPR) + ~120 VGPR  -- well under the 256/thread cap.
// (R4/R5's 4-row tile hit the 2-wave/EU register cap -> scratch spill thrash:
//  11.5 GB HBM writes/dispatch with all pipes idle. Do not enlarge acc.)
// A: VGPR prefetch -> XOR-swizzled LDS, 128 B/px (hi64|lo64), no pad.
// B: register double-clocked, 144 B/co (hi64|lo64|pad16).
// OUTMODE 0: packed interleaved hi/lo bf16 (interior). OUTMODE 1: fp32 NCHW.
// ---------------------------------------------------------------------------
#define ABYTES 33792            // 264 px * 128 B
#define BBOFF  33792
#define SMEMB  52224            // + 128 co * 144 B

template <int COUT, int OUTMODE>
__global__ __launch_bounds__(256, 2) void conv3x3_mfma(
    const unsigned short* __restrict__ P, const unsigned short* __restrict__ Wt,
    const float* __restrict__ gam, const float* __restrict__ bet,
    unsigned short* __restrict__ Opk, float* __restrict__ Ofp) {
  const int bid = blockIdx.x;
  int nblk, mb;
  if (COUT == 256) { nblk = bid >> 10; mb = bid & 1023; }   // same XCD for both halves
  else             { nblk = 0;         mb = bid; }
  const int b  = mb >> 5;
  const int yt = mb & 31;
  const int Y0 = yt * 2;               // first output row (= first padded in row)

  const int tid  = threadIdx.x;
  const int lane = tid & 63;
  const int wv   = tid >> 6;
  const int l15  = lane & 15;
  const int quad = lane >> 4;
  const int mhalf = (wv & 1) * 64;
  const int nbase = (wv >> 1) * 64;

  __shared__ __align__(16) char smem[SMEMB];

  int pbase[4];
#pragma unroll
  for (int mi = 0; mi < 4; ++mi) {
    int px = mhalf + mi * 16 + l15;
    pbase[mi] = (px >> 6) * 66 + (px & 63);
  }
  int boff[4];
#pragma unroll
  for (int ni = 0; ni < 4; ++ni)
    boff[ni] = (nbase + ni * 16 + l15) * 144 + quad * 16;

  f32x4 acc[4][4];
#pragma unroll
  for (int mi = 0; mi < 4; ++mi)
#pragma unroll
    for (int ni = 0; ni < 4; ++ni) acc[mi][ni] = (f32x4)0.f;

  const size_t ibase = (size_t)(b * 66 + Y0) * 66;

  uint4 ipref[9], bpref[4];

  // A staging: 264 px * 8 groups of 16 B = 2112 slots. Global coalesced,
  // LDS write swizzled: slot gs = g ^ (p & 7)  -> conflict-free reads.
  auto loadI = [&](int cc) {
#pragma unroll
    for (int j = 0; j < 9; ++j) {
      int idx = tid + j * 256;
      if (idx < 2112) {
        int p = idx >> 3, g = idx & 7;
        size_t goff = (ibase + p) * 512 + (g < 4 ? cc * 32 + g * 8
                                                 : 256 + cc * 32 + (g - 4) * 8);
        ipref[j] = *(const uint4*)(P + goff);
      }
    }
  };
  auto writeI = [&]() {
#pragma unroll
    for (int j = 0; j < 9; ++j) {
      int idx = tid + j * 256;
      if (idx < 2112) {
        int p = idx >> 3, g = idx & 7;
        int gs = g ^ (p & 7);
        *(uint4*)(smem + p * 128 + gs * 16) = ipref[j];
      }
    }
  };
  auto loadB = [&](int tt, int cc) {
#pragma unroll
    for (int j = 0; j < 4; ++j) {
      int idx = tid + j * 256;
      int co = idx >> 3, g = idx & 7;
      size_t goff = ((size_t)tt * COUT + nblk * 128 + co) * 512 +
                    (g < 4 ? cc * 32 + g * 8 : 256 + cc * 32 + (g - 4) * 8);
      bpref[j] = *(const uint4*)(Wt + goff);
    }
  };
  auto writeB = [&]() {
#pragma unroll
    for (int j = 0; j < 4; ++j) {
      int idx = tid + j * 256;
      int co = idx >> 3, g = idx & 7;
      *(uint4*)(smem + BBOFF + co * 144 + g * 16) = bpref[j];
    }
  };

  // ---- prologue ----
  loadI(0);
  loadB(0, 0);
  writeI();
  writeB();
  loadB(1, 0);
  __syncthreads();

  for (int c8 = 0; c8 < 8; ++c8) {
#pragma unroll
    for (int t = 0; t < 9; ++t) {
      if (t == 7 && c8 < 7) loadI(c8 + 1);

      const int offt = (t / 3) * 66 + (t % 3);
      bf16x8 bh[4], bl[4];
#pragma unroll
      for (int ni = 0; ni < 4; ++ni) {
        const char* bp = smem + BBOFF + boff[ni];
        bh[ni] = *(const bf16x8*)bp;
        bl[ni] = *(const bf16x8*)(bp + 64);
      }
#pragma unroll
      for (int mi = 0; mi < 4; ++mi) {
        int p  = pbase[mi] + offt;
        int sw = (quad ^ (p & 7)) << 4;
        bf16x8 ah = *(const bf16x8*)(smem + p * 128 + sw);
        bf16x8 al = *(const bf16x8*)(smem + p * 128 + (sw ^ 64));
#pragma unroll
        for (int ni = 0; ni < 4; ++ni) {
          acc[mi][ni] = __builtin_amdgcn_mfma_f32_16x16x32_bf16(ah, bh[ni], acc[mi][ni], 0, 0, 0);
          acc[mi][ni] = __builtin_amdgcn_mfma_f32_16x16x32_bf16(al, bh[ni], acc[mi][ni], 0, 0, 0);
          acc[mi][ni] = __builtin_amdgcn_mfma_f32_16x16x32_bf16(ah, bl[ni], acc[mi][ni], 0, 0, 0);
        }
      }

      if (!(c8 == 7 && t == 8)) {
        __syncthreads();
        writeB();
        if (t == 8) writeI();
        int nt = t + 2, nc = c8;
        if (nt >= 9) { nt -= 9; ++nc; }
        if (nc > 7) { nc = 7; nt = 8; }
        loadB(nt, nc);
        __syncthreads();
      }
    }
  }

  // ---- epilogue: BN + ReLU ----
  __syncthreads();
  float sc[4], bi[4];
#pragma unroll
  for (int ni = 0; ni < 4; ++ni) {
    int co = nblk * 128 + nbase + ni * 16 + l15;
    sc[ni] = gam[co] * BN_SCALE;
    bi[ni] = bet[co];
  }

  if (OUTMODE == 0) {
    // 2 chunks = 2 output rows; LDS row: 64 px * (hi256|lo256|pad16) = 528 B
    for (int c = 0; c < 2; ++c) {
      if ((wv & 1) == c) {
#pragma unroll
        for (int mi = 0; mi < 4; ++mi) {
#pragma unroll
          for (int ni = 0; ni < 4; ++ni) {
            int cofs = (nbase + ni * 16 + l15) * 2;
#pragma unroll
            for (int r = 0; r < 4; ++r) {
              int col = mi * 16 + quad * 4 + r;
              float v = fmaxf(acc[mi][ni][r] * sc[ni] + bi[ni], 0.f);
              unsigned short hb = f2bf(v);
              *(unsigned short*)(smem + col * 528 + cofs)       = hb;
              *(unsigned short*)(smem + col * 528 + 256 + cofs) = f2bf(v - bf2f(hb));
            }
          }
        }
      }
      __syncthreads();
#pragma unroll
      for (int j = 0; j < 8; ++j) {
        int idx = tid + j * 256;
        int px = idx >> 5, s = idx & 31;
        uint4 d = *(const uint4*)(smem + px * 528 + s * 16);
        size_t pg = (size_t)(b * 66 + Y0 + c + 1) * 66 + (px + 1);
        char* dst = (char*)Opk + pg * 1024 + nblk * 256 + s * 16 + ((s & 16) ? 256 : 0);
        *(uint4*)dst = d;
      }
      __syncthreads();
    }
  } else {
    // fp32 NCHW: 2 chunks of one row x 128 co; LDS: co*272 + col*4
    for (int c = 0; c < 2; ++c) {
      if ((wv & 1) == c) {
#pragma unroll
        for (int mi = 0; mi < 4; ++mi) {
          int pl = mi * 16 + quad * 4;
#pragma unroll
          for (int ni = 0; ni < 4; ++ni) {
            int co = nbase + ni * 16 + l15;
            f32x4 vv;
#pragma unroll
            for (int r = 0; r < 4; ++r)
              vv[r] = fmaxf(acc[mi][ni][r] * sc[ni] + bi[ni], 0.f);
            *(f32x4*)(smem + co * 272 + pl * 4) = vv;
          }
        }
      }
      __syncthreads();
#pragma unroll
      for (int j = 0; j < 8; ++j) {
        int idx = tid + j * 256;
        int co = idx >> 4, g = idx & 15;
        f32x4 d = *(const f32x4*)(smem + co * 272 + g * 16);
        size_t o = ((size_t)b * COUT + nblk * 128 + co) * 4096 + (Y0 + c) * 64 + g * 4;
        *(f32x4*)(Ofp + o) = d;
      }
      __syncthreads();
    }
  }
}

// ---------------------------------------------------------------------------
// 1x1 conv + bias (+ optional softplus), fp32 NCHW input
// ---------------------------------------------------------------------------
template <int CO, int CIN>
__global__ __launch_bounds__(256) void conv1x1_kernel(
    const float* __restrict__ in, const float* __restrict__ w,
    const float* __restrict__ bias, float* __restrict__ out, int do_softplus) {
  __shared__ float s_w[CO * CIN];
  const int b   = blockIdx.x >> 4;
  const int pix = ((blockIdx.x & 15) << 8) + threadIdx.x;
  for (int i = threadIdx.x; i < CO * CIN; i += 256) s_w[i] = w[i];
  __syncthreads();

  float acc[CO];
#pragma unroll
  for (int co = 0; co < CO; ++co) acc[co] = 0.f;

  const float* ip = in + (size_t)b * CIN * HW_ + pix;
  for (int ci = 0; ci < CIN; ++ci) {
    float v = ip[(size_t)ci * HW_];
#pragma unroll
    for (int co = 0; co < CO; ++co) acc[co] = fmaf(v, s_w[co * CIN + ci], acc[co]);
  }
  float* op = out + (size_t)b * CO * HW_ + pix;
#pragma unroll
  for (int co = 0; co < CO; ++co) {
    float x = acc[co] + bias[co];
    if (do_softplus) x = fmaxf(x, 0.f) + log1pf(expf(-fabsf(x)));
    op[(size_t)co * HW_] = x;
  }
}

// ---------------------------------------------------------------------------
// soft-argmax over each (b,k) 64x64 heatmap
// ---------------------------------------------------------------------------
__global__ __launch_bounds__(256) void soft_argmax_kernel(
    const float* __restrict__ heat, float* __restrict__ cg,
    float* __restrict__ scores) {
  const int bk = blockIdx.x;
  const float* h = heat + (size_t)bk * HW_;
  const int tid = threadIdx.x;
  __shared__ float sred[256];

  float v[16];
  float lmax = -INFINITY;
#pragma unroll
  for (int i = 0; i < 16; ++i) {
    v[i] = h[tid + (i << 8)];
    lmax = fmaxf(lmax, v[i]);
  }
  sred[tid] = lmax; __syncthreads();
  for (int s = 128; s > 0; s >>= 1) {
    if (tid < s) sred[tid] = fmaxf(sred[tid], sred[tid + s]);
    __syncthreads();
  }
  const float m = sred[0];
  __syncthreads();

  float s = 0.f, sx = 0.f, sy = 0.f;
#pragma unroll
  for (int i = 0; i < 16; ++i) {
    int idx = tid + (i << 8);
    float e = expf(v[i] - m);
    s += e;
    sx += e * (float)(idx & 63);
    sy += e * (float)(idx >> 6);
  }
  sred[tid] = s; __syncthreads();
  for (int st = 128; st > 0; st >>= 1) { if (tid < st) sred[tid] += sred[tid + st]; __syncthreads(); }
  const float S = sred[0]; __syncthreads();
  sred[tid] = sx; __syncthreads();
  for (int st = 128; st > 0; st >>= 1) { if (tid < st) sred[tid] += sred[tid + st]; __syncthreads(); }
  const float SX = sred[0]; __syncthreads();
  sred[tid] = sy; __syncthreads();
  for (int st = 128; st > 0; st >>= 1) { if (tid < st) sred[tid] += sred[tid + st]; __syncthreads(); }
  const float SY = sred[0];

  if (tid == 0) {
    cg[bk * 2]     = SX / S;
    cg[bk * 2 + 1] = SY / S;
    scores[bk]     = m;
  }
}

// ---------------------------------------------------------------------------
// local refine + blend + bilinear offset sampling + final coords; writes fw.
// ---------------------------------------------------------------------------
__global__ void refine_kernel(
    const float* __restrict__ heat, const float* __restrict__ off,
    const float* __restrict__ cg, const float* __restrict__ alpha_p,
    const float* __restrict__ fusion_p, float* __restrict__ coords_out,
    float* __restrict__ fw_out) {
  const int kp = blockIdx.x * 64 + threadIdx.x;
  const float fw = 1.f / (1.f + expf(-fusion_p[0]));
  if (kp == 0) fw_out[0] = fw;
  if (kp >= B_ * K_) return;

  const float a = 1.f / (1.f + expf(-alpha_p[0]));
  const float* h = heat + (size_t)kp * HW_;
  const float cgx = cg[kp * 2];
  const float cgy = cg[kp * 2 + 1];
  const int px = (int)rintf(fminf(fmaxf(cgx, 0.f), 63.f));
  const int py = (int)rintf(fminf(fmaxf(cgy, 0.f), 63.f));

  float vals[25];
  float m = -INFINITY;
#pragma unroll
  for (int dy = 0; dy < 5; ++dy) {
    int ya = py + dy - 2;
    int yc = min(max(ya, 0), 63);
#pragma unroll
    for (int dx = 0; dx < 5; ++dx) {
      int xa = px + dx - 2;
      int xc = min(max(xa, 0), 63);
      bool inb = (ya >= 0) && (ya < H_) && (xa >= 0) && (xa < W_);
      float val = inb ? h[yc * W_ + xc] : -INFINITY;
      vals[dy * 5 + dx] = val;
      m = fmaxf(m, val);
    }
  }
  float s = 0.f, rx = 0.f, ry = 0.f;
#pragma unroll
  for (int dy = 0; dy < 5; ++dy) {
    int ya = py + dy - 2;
    int yc = min(max(ya, 0), 63);
#pragma unroll
    for (int dx = 0; dx < 5; ++dx) {
      int xa = px + dx - 2;
      int xc = min(max(xa, 0), 63);
      float e = expf(vals[dy * 5 + dx] - m);
      s += e;
      rx += e * (float)xc;
      ry += e * (float)yc;
    }
  }
  rx /= s; ry /= s;

  float cx = a * cgx + (1.f - a) * rx;
  float cy = a * cgy + (1.f - a) * ry;

  const float ix = fminf(fmaxf(cx, 0.f), 63.f);
  const float iy = fminf(fmaxf(cy, 0.f), 63.f);
  const float x0 = floorf(ix), y0 = floorf(iy);
  const float wx = ix - x0, wy = iy - y0;
  const int x0i = min(max((int)x0, 0), 63);
  const int x1i = min(x0i + 1, 63);
  const int y0i = min(max((int)y0, 0), 63);
  const int y1i = min(y0i + 1, 63);

  float smp[2];
#pragma unroll
  for (int ch = 0; ch < 2; ++ch) {
    const float* oc = off + ((size_t)kp * 2 + ch) * HW_;
    float v00 = oc[y0i * W_ + x0i];
    float v01 = oc[y0i * W_ + x1i];
    float v10 = oc[y1i * W_ + x0i];
    float v11 = oc[y1i * W_ + x1i];
    smp[ch] = (1.f - wy) * ((1.f - wx) * v00 + wx * v01)
            + wy * ((1.f - wx) * v10 + wx * v11);
  }
  cx += fw * smp[0];
  cy += fw * smp[1];
  coords_out[kp * 2]     = cx;
  coords_out[kp * 2 + 1] = cy;
}

// ---------------------------------------------------------------------------
extern "C" void kernel_launch(void* const* d_in, const int* in_sizes, int n_in,
                              void* d_out, int out_size, void* d_ws, size_t ws_size,
                              hipStream_t stream) {
  const float* x    = (const float*)d_in[0];
  const float* w_s1 = (const float*)d_in[1];
  const float* g_s1 = (const float*)d_in[2];
  const float* b_s1 = (const float*)d_in[3];
  const float* w_s2 = (const float*)d_in[4];
  const float* g_s2 = (const float*)d_in[5];
  const float* b_s2 = (const float*)d_in[6];
  const float* w_h1 = (const float*)d_in[7];
  const float* g_h1 = (const float*)d_in[8];
  const float* b_h1 = (const float*)d_in[9];
  const float* w_h2 = (const float*)d_in[10];
  const float* c_h2 = (const float*)d_in[11];
  const float* w_o1 = (const float*)d_in[12];
  const float* g_o1 = (const float*)d_in[13];
  const float* b_o1 = (const float*)d_in[14];
  const float* w_o2 = (const float*)d_in[15];
  const float* c_o2 = (const float*)d_in[16];
  const float* w_v1 = (const float*)d_in[17];
  const float* g_v1 = (const float*)d_in[18];
  const float* b_v1 = (const float*)d_in[19];
  const float* w_v2 = (const float*)d_in[20];
  const float* c_v2 = (const float*)d_in[21];
  const float* alpha  = (const float*)d_in[22];
  const float* fusion = (const float*)d_in[23];

  float* out = (float*)d_out;
  char*  ws  = (char*)d_ws;

  unsigned short* XP  = (unsigned short*)(ws + XP_OFF);
  unsigned short* S1  = (unsigned short*)(ws + S1_OFF);
  unsigned short* S2  = (unsigned short*)(ws + S2_OFF);
  unsigned short* WS1 = (unsigned short*)(ws + WS1_OFF);
  unsigned short* WS2 = (unsigned short*)(ws + WS2_OFF);
  unsigned short* WH1 = (unsigned short*)(ws + WH1_OFF);
  unsigned short* WO1 = (unsigned short*)(ws + WO1_OFF);
  unsigned short* WV1 = (unsigned short*)(ws + WV1_OFF);
  float* F0  = (float*)(ws + 0);        // overlays XP (dead after s1 conv)
  float* cgb = (float*)(ws + CG_OFF);

  dim3 blk(256);

  // ---- pack inputs & weights, zero halos ----
  pack_x<<<32 * 66, blk, 0, stream>>>(x, XP);
  pack_w<<<2304, blk, 0, stream>>>(w_s1, WS1, 256);
  pack_w<<<2304, blk, 0, stream>>>(w_s2, WS2, 256);
  pack_w<<<2304, blk, 0, stream>>>(w_h1, WH1, 256);
  pack_w<<<2304, blk, 0, stream>>>(w_o1, WO1, 256);
  pack_w<<<1152, blk, 0, stream>>>(w_v1, WV1, 128);
  zero_border<<<16640, blk, 0, stream>>>(S1);
  zero_border<<<16640, blk, 0, stream>>>(S2);

  // ---- backbone convs (split-bf16 3-pass MFMA) ----
  conv3x3_mfma<256, 0><<<2048, blk, 0, stream>>>(XP, WS1, g_s1, b_s1, S1, nullptr);
  conv3x3_mfma<256, 0><<<2048, blk, 0, stream>>>(S1, WS2, g_s2, b_s2, S2, nullptr);
  conv3x3_mfma<256, 1><<<2048, blk, 0, stream>>>(S2, WH1, g_h1, b_h1, nullptr, F0);
  conv1x1_kernel<17, 256><<<512, blk, 0, stream>>>(F0, w_h2, c_h2, out + HEAT_OFF, 0);
  conv3x3_mfma<256, 1><<<2048, blk, 0, stream>>>(S2, WO1, g_o1, b_o1, nullptr, F0);
  conv1x1_kernel<34, 256><<<512, blk, 0, stream>>>(F0, w_o2, c_o2, out + OFF_OFF, 0);
  conv3x3_mfma<128, 1><<<1024, blk, 0, stream>>>(S2, WV1, g_v1, b_v1, nullptr, F0);
  conv1x1_kernel<17, 128><<<512, blk, 0, stream>>>(F0, w_v2, c_v2, out + VAR_OFF, 1);

  // ---- heads ----
  soft_argmax_kernel<<<544, blk, 0, stream>>>(out + HEAT_OFF, cgb, out + SCORE_OFF);
  refine_kernel<<<9, dim3(64), 0, stream>>>(out + HEAT_OFF, out + OFF_OFF, cgb,
                                            alpha, fusion,
                                            out + COORD_OFF, out + FW_OFF);
}